// Round 5
// baseline (262.914 us; speedup 1.0000x reference)
//
#include <hip/hip_runtime.h>
#include <math.h>

#define Bn 8
#define Nn 2048
#define FIn 256
#define FOn 128

typedef __attribute__((ext_vector_type(8))) short short8;
typedef __attribute__((ext_vector_type(4))) float f32x4;

__device__ __forceinline__ unsigned short f2bf(float x){
    union { float f; unsigned u; } v; v.f = x;
    unsigned r = v.u + 0x7fffu + ((v.u >> 16) & 1u);
    return (unsigned short)(r >> 16);
}

// K0: WT[o][k] = bf16(W[k][o])   (128 x 256)
__global__ void k0_wt(const float* __restrict__ W, unsigned short* __restrict__ WT){
    int o = blockIdx.x, k = threadIdx.x;
    WT[o*FIn + k] = f2bf(W[k*FOn + o]);
}

// K1: Wh = h @ W via bf16 MFMA; emits WhT (bf16, transposed) + s1/s2.
// 32 rows/block, grid 512 (2 blocks/CU). 4 waves = 2 row-groups x 2 col-halves.
__global__ __launch_bounds__(256) void k1_gemm(const float* __restrict__ h,
        const unsigned short* __restrict__ WT, const float* __restrict__ a,
        unsigned short* __restrict__ WhT, float* __restrict__ s1, float* __restrict__ s2){
    __shared__ __align__(16) unsigned short tr[128][48];
    __shared__ float ps1[2][32], ps2[2][32];
    int t = threadIdx.x, lane = t & 63, w = t >> 6;
    int rg = w >> 1, ch = w & 1;
    int l16 = lane & 15, khalf = (lane >> 4) * 8;
    long g0 = (long)blockIdx.x * 32;
    int b = (int)(g0 >> 11);
    int i0 = (int)(g0 & 2047);
    long row = g0 + rg*16 + l16;
    f32x4 acc[4];
    #pragma unroll
    for (int nf=0;nf<4;nf++) acc[nf] = (f32x4){0.f,0.f,0.f,0.f};
    #pragma unroll
    for (int ks=0; ks<8; ks++){
        int kb = ks*32 + khalf;
        const float4* hp = (const float4*)(h + row*FIn + kb);
        float4 h0 = hp[0], h1 = hp[1];
        short8 af;
        af[0]=(short)f2bf(h0.x); af[1]=(short)f2bf(h0.y); af[2]=(short)f2bf(h0.z); af[3]=(short)f2bf(h0.w);
        af[4]=(short)f2bf(h1.x); af[5]=(short)f2bf(h1.y); af[6]=(short)f2bf(h1.z); af[7]=(short)f2bf(h1.w);
        #pragma unroll
        for (int nf=0;nf<4;nf++){
            short8 bfv = *(const short8*)(WT + (ch*64 + nf*16 + l16)*FIn + kb);
            acc[nf] = __builtin_amdgcn_mfma_f32_16x16x32_bf16(af, bfv, acc[nf], 0, 0, 0);
        }
    }
    {
        float a1v[4], a2v[4];
        #pragma unroll
        for (int nf=0;nf<4;nf++){
            a1v[nf] = a[ch*64 + nf*16 + l16];
            a2v[nf] = a[FOn + ch*64 + nf*16 + l16];
        }
        #pragma unroll
        for (int r=0;r<4;r++){
            float u1 = 0.f, u2 = 0.f;
            #pragma unroll
            for (int nf=0;nf<4;nf++){ u1 = fmaf(acc[nf][r], a1v[nf], u1); u2 = fmaf(acc[nf][r], a2v[nf], u2); }
            u1 += __shfl_xor(u1, 1); u1 += __shfl_xor(u1, 2); u1 += __shfl_xor(u1, 4); u1 += __shfl_xor(u1, 8);
            u2 += __shfl_xor(u2, 1); u2 += __shfl_xor(u2, 2); u2 += __shfl_xor(u2, 4); u2 += __shfl_xor(u2, 8);
            if (l16 == 0){
                int rloc = rg*16 + ((lane>>4)<<2) + r;
                ps1[ch][rloc] = u1; ps2[ch][rloc] = u2;
            }
        }
    }
    int rbase = rg*16 + ((lane>>4)<<2);
    #pragma unroll
    for (int nf=0;nf<4;nf++)
        #pragma unroll
        for (int r=0;r<4;r++)
            tr[ch*64 + nf*16 + l16][rbase + r] = f2bf(acc[nf][r]);
    __syncthreads();
    if (t < 32){
        s1[g0 + t] = ps1[0][t] + ps1[1][t];
        s2[g0 + t] = ps2[0][t] + ps2[1][t];
    }
    int o = t >> 1, seg = t & 1;
    short8 v0 = *(const short8*)&tr[o][seg*16];
    short8 v1 = *(const short8*)&tr[o][seg*16 + 8];
    unsigned short* dst = WhT + ((long)(b*FOn + o))*Nn + i0 + seg*16;
    *(short8*)(dst)     = v0;
    *(short8*)(dst + 8) = v1;
}

// K2: s2max[b] = max_j s2[b][j]  (8 blocks x 256 threads)
__global__ __launch_bounds__(256) void k2_s2max(const float* __restrict__ s2, float* __restrict__ s2m){
    __shared__ float red[4];
    int b = blockIdx.x, t = threadIdx.x;
    float m = -1e30f;
    #pragma unroll
    for (int k=0;k<8;k++) m = fmaxf(m, s2[b*Nn + t + k*256]);
    m = fmaxf(m, __shfl_xor(m, 1));
    m = fmaxf(m, __shfl_xor(m, 2));
    m = fmaxf(m, __shfl_xor(m, 4));
    m = fmaxf(m, __shfl_xor(m, 8));
    m = fmaxf(m, __shfl_xor(m, 16));
    m = fmaxf(m, __shfl_xor(m, 32));
    if ((t & 63) == 0) red[t >> 6] = m;
    __syncthreads();
    if (t == 0) s2m[b] = fmaxf(fmaxf(red[0], red[1]), fmaxf(red[2], red[3]));
}

// K3 v5: global-shift softmax attention. Block = (b, 32-row i-tile), 512 threads = 8 waves.
// 2 supersteps of 1024 j-cols. Phase-S: thread (q,c) owns row q x tile c (64 j):
// streaming p = adj ? exp(leaky(s1+s2) - M) : 0, M = leaky(s1 + s2max) (exact upper
// bound via monotone leaky => softmax shift-invariant). P -> LDS (bank-uniform layout).
// Phase-M: D = out^T orientation; A = WhT rows read straight from L2 (full 128B lines),
// B = P from LDS. 3 barriers total. adj: full-superstep (16xint4) register prefetch.
__global__ __launch_bounds__(512, 4) void k3_flash(const int* __restrict__ adj,
        const unsigned short* __restrict__ WhT, const float* __restrict__ s1g,
        const float* __restrict__ s2g, const float* __restrict__ s2m,
        float* __restrict__ out){
    __shared__ unsigned int ptf[16*1156];   // 16 tiles x (32 rows x 36 dw + 4) = 73,984 B
    __shared__ float l_s[32];
    int t = threadIdx.x, lane = t & 63, w = t >> 6;
    int bid = blockIdx.x;
    int b = bid & 7;                 // XCD pin: per-b WhT slice resident in one L2
    int i0 = (bid >> 3) * 32;
    int q = t >> 4, c = t & 15;      // score row / col-tile
    int l16 = lane & 15, hh = lane >> 4;
    float s1r = s1g[b*Nn + i0 + q];
    float Mx = s1r + s2m[b];
    Mx = fmaxf(Mx, 0.2f*Mx);         // = leaky(s1r + s2max), monotone => >= all row scores
    float lsum = 0.f;
    f32x4 acc0 = (f32x4){0.f,0.f,0.f,0.f};
    f32x4 acc1 = (f32x4){0.f,0.f,0.f,0.f};
    const int*   ajb = adj + ((long)(b*Nn + i0 + q))*Nn + c*64;
    const float* s2b = s2g + b*Nn + c*64;
    const unsigned short* Ab = WhT + ((long)(b*FOn + w*16 + l16))*Nn + hh*8;
    unsigned int pbase = c*1156 + q*36;
    int4 aj[16];

#define SCORES(SS)                                                              \
    {                                                                           \
        uint4 pw;                                                               \
        _Pragma("unroll")                                                       \
        for (int k=0;k<16;k++){                                                 \
            int4 av = aj[k];                                                    \
            float4 s2c = *(const float4*)(s2b + (SS)*1024 + k*4);               \
            float x0 = s1r + s2c.x; x0 = fmaxf(x0, 0.2f*x0);                    \
            float x1 = s1r + s2c.y; x1 = fmaxf(x1, 0.2f*x1);                    \
            float x2 = s1r + s2c.z; x2 = fmaxf(x2, 0.2f*x2);                    \
            float x3 = s1r + s2c.w; x3 = fmaxf(x3, 0.2f*x3);                    \
            float p0 = av.x > 0 ? __expf(x0 - Mx) : 0.f;                        \
            float p1 = av.y > 0 ? __expf(x1 - Mx) : 0.f;                        \
            float p2 = av.z > 0 ? __expf(x2 - Mx) : 0.f;                        \
            float p3 = av.w > 0 ? __expf(x3 - Mx) : 0.f;                        \
            lsum += (p0 + p1) + (p2 + p3);                                      \
            unsigned lo = (unsigned)f2bf(p0) | ((unsigned)f2bf(p1) << 16);      \
            unsigned hi = (unsigned)f2bf(p2) | ((unsigned)f2bf(p3) << 16);      \
            if (k & 1){ pw.z = lo; pw.w = hi;                                   \
                        *(uint4*)&ptf[pbase + (k>>1)*4] = pw; }                 \
            else      { pw.x = lo; pw.y = hi; }                                 \
        }                                                                       \
    }

#define MFMAPH(SS)                                                              \
    {                                                                           \
        const unsigned short* Abs = Ab + (SS)*1024;                             \
        short8 pf0[2], pf1[2];                                                  \
        pf0[0] = *(const short8*)(Abs);         pf1[0] = *(const short8*)(Abs + 32); \
        pf0[1] = *(const short8*)(Abs + 64);    pf1[1] = *(const short8*)(Abs + 96); \
        _Pragma("unroll")                                                       \
        for (int jt=0; jt<16; jt++){                                            \
            short8 cA0 = pf0[jt&1], cA1 = pf1[jt&1];                            \
            if (jt < 14){                                                       \
                pf0[jt&1] = *(const short8*)(Abs + (jt+2)*64);                  \
                pf1[jt&1] = *(const short8*)(Abs + (jt+2)*64 + 32);             \
            }                                                                   \
            unsigned bb = jt*1156;                                              \
            short8 b00 = *(const short8*)&ptf[bb + l16*36 + hh*4];              \
            short8 b01 = *(const short8*)&ptf[bb + l16*36 + (4+hh)*4];          \
            short8 b10 = *(const short8*)&ptf[bb + (16+l16)*36 + hh*4];         \
            short8 b11 = *(const short8*)&ptf[bb + (16+l16)*36 + (4+hh)*4];     \
            acc0 = __builtin_amdgcn_mfma_f32_16x16x32_bf16(cA0, b00, acc0, 0, 0, 0); \
            acc0 = __builtin_amdgcn_mfma_f32_16x16x32_bf16(cA1, b01, acc0, 0, 0, 0); \
            acc1 = __builtin_amdgcn_mfma_f32_16x16x32_bf16(cA0, b10, acc1, 0, 0, 0); \
            acc1 = __builtin_amdgcn_mfma_f32_16x16x32_bf16(cA1, b11, acc1, 0, 0, 0); \
        }                                                                       \
    }

    // prologue: adj superstep-0 prefetch (16 x int4 in flight)
    #pragma unroll
    for (int k=0;k<16;k++) aj[k] = *(const int4*)(ajb + k*4);
    SCORES(0)
    // re-issue adj for superstep 1: hides under barrier + entire MFMA phase 0
    #pragma unroll
    for (int k=0;k<16;k++) aj[k] = *(const int4*)(ajb + 1024 + k*4);
    __syncthreads();
    MFMAPH(0)
    __syncthreads();
    SCORES(1)
    // row-sum: reduce lsum over the 16 c-lanes of each row (single chain per kernel)
    lsum += __shfl_xor(lsum, 1);
    lsum += __shfl_xor(lsum, 2);
    lsum += __shfl_xor(lsum, 4);
    lsum += __shfl_xor(lsum, 8);
    if (c == 0) l_s[q] = lsum;
    __syncthreads();
    MFMAPH(1)
#undef SCORES
#undef MFMAPH

    // epilogue: D = out^T tile: col = i = l16 (+16 for acc1), row o = w*16 + hh*4 + reg
    float li0 = 1.f / l_s[l16];
    float li1 = 1.f / l_s[16 + l16];
    float4 o0, o1;
    #pragma unroll
    for (int r=0;r<4;r++){
        float v0 = acc0[r] * li0;
        float v1 = acc1[r] * li1;
        ((float*)&o0)[r] = v0 > 0.f ? v0 : (__expf(v0) - 1.f);
        ((float*)&o1)[r] = v1 > 0.f ? v1 : (__expf(v1) - 1.f);
    }
    *(float4*)(out + ((long)(b*Nn + i0 + l16))*FOn + w*16 + hh*4)      = o0;
    *(float4*)(out + ((long)(b*Nn + i0 + 16 + l16))*FOn + w*16 + hh*4) = o1;
}

extern "C" void kernel_launch(void* const* d_in, const int* in_sizes, int n_in,
                              void* d_out, int out_size, void* d_ws, size_t ws_size,
                              hipStream_t stream){
    const float* h  = (const float*)d_in[0];
    const int* adj  = (const int*)d_in[1];
    const float* W  = (const float*)d_in[2];
    const float* a  = (const float*)d_in[3];
    float* out = (float*)d_out;
    char* ws = (char*)d_ws;
    unsigned short* WT  = (unsigned short*)(ws);                   //    65,536 B
    unsigned short* WhT = (unsigned short*)(ws + 65536);           // 4,194,304 B
    float* s1           = (float*)(ws + 65536 + 4194304);          //    65,536 B
    float* s2           = (float*)(ws + 65536 + 4194304 + 65536);  //    65,536 B
    float* s2m          = (float*)(ws + 65536 + 4194304 + 131072); //        32 B

    k0_wt    <<<128, 256, 0, stream>>>(W, WT);
    k1_gemm  <<<512, 256, 0, stream>>>(h, WT, a, WhT, s1, s2);
    k2_s2max <<<Bn,  256, 0, stream>>>(s2, s2m);
    k3_flash <<<512, 512, 0, stream>>>(adj, WhT, s1, s2, s2m, out);
}